// Round 9
// baseline (558.890 us; speedup 1.0000x reference)
//
#include <hip/hip_runtime.h>

// 16-qubit, depth-4, batch-512 statevector simulator — 6-sweep, packed-FP32,
// transpose-balanced: B sweeps do 7 gates + 1 transpose (was 11 + 2);
// A sweeps do 9 gates + 1 transpose (was 5 + 0).  Only q15,q14,q13 are
// B-forced and q3,q2,q1 A-forced; the 8 middle qubits (q11..q4) are split
// 4/4 so each partition needs exactly one extra register arrangement.
//
// State: 512 x 65536 complex64 = 256 MiB in d_ws.
// Reference qubit q <-> flat-index bit beta = 15-q.
// Memory layout per batch: amp with basis index g stored at m = (g>>3) | ((g&7)<<13).
//
// Partition A (blocks fix g bits 0..2): local j = m bits 0..12, j_b = g_{b+3}.
// Partition B (blocks fix g bits 12..14): local d: d0..8 = g3..11, d9 = g15,
//   d10..12 = g0..2.
//
// Chain perm (16 CNOTs), inverse: s_b = f_b^f_{b+1} (b=0..13),
//   s14 = f14^f15^f0, s15 = f15^f0.  Split: main (A-local) o tail (B-local
//   register rename permB).  Generic LDS transpose: stage S[slot(j)] = amp[j]
//   with slot(j) = j ^ (((j>>5)&7)<<1); any write/read arrangement pair works.
// Schedule (6 sweeps):
//   1. qc_B1_gen:   analytic gen (L0+chain0 folded, product tree) + L1 x7.
//   2. qc_A_lite(1): L1 x9 + main1.
//   3. qc_B_heavy(2): tail1 + L2 x7.
//   4. qc_A_lite(2): L2 x9 + main2.
//   5. qc_B_heavy(3): tail2 + L3 x7.
//   6. qc_A_final:  L3 x9 + expZ (main3.tail3 relabel, arr2-layout buckets).

#define NQ 16
#define TPB 256

typedef float __attribute__((ext_vector_type(2))) f2;   // (re, im)

__device__ __forceinline__ f2 f2s(float s) { return (f2){s, s}; }

// a (*) b  (complex mul, packed: pk_mul + pk_fma)
__device__ __forceinline__ f2 cmulpk(f2 a, f2 b) {
    f2 bs = { -b.y, b.x };
    f2 r = f2s(a.x) * b;
    return __builtin_elementwise_fma(f2s(a.y), bs, r);
}

// U = RY(t2) * RX(t1) * RZ(t0), row-major [u00,u01,u10,u11]
__device__ __forceinline__ void computeU(const float* params, int layer, int q, f2* U) {
    const float* p = params + (layer*NQ + q)*3;
    float s0, c0, s1, c1, s2, c2;
    sincosf(0.5f*p[0], &s0, &c0);
    sincosf(0.5f*p[1], &s1, &c1);
    sincosf(0.5f*p[2], &s2, &c2);
    f2 m00 = { c1*c0, -c1*s0};
    f2 m01 = { s1*s0, -s1*c0};
    f2 m10 = {-s1*s0, -s1*c0};
    f2 m11 = { c1*c0,  c1*s0};
    U[0] = c2*m00 - s2*m10;
    U[1] = c2*m01 - s2*m11;
    U[2] = s2*m00 + c2*m10;
    U[3] = s2*m01 + c2*m11;
}

// 1q gate on register array A[32], pairing a <-> a|MASK.  8 packed ops/pair.
template<int MASK>
__device__ __forceinline__ void gate32(f2* A, f2 u00, f2 u01, f2 u10, f2 u11) {
    #pragma unroll
    for (int a = 0; a < 32; ++a) {
        if (!(a & MASK)) {
            f2 x = A[a], y = A[a | MASK];
            f2 xs = { -x.y, x.x };
            f2 ys = { -y.y, y.x };
            f2 nx = f2s(u00.x) * x;
            nx = __builtin_elementwise_fma(f2s(u00.y), xs, nx);
            nx = __builtin_elementwise_fma(f2s(u01.x), y,  nx);
            nx = __builtin_elementwise_fma(f2s(u01.y), ys, nx);
            f2 ny = f2s(u10.x) * x;
            ny = __builtin_elementwise_fma(f2s(u10.y), xs, ny);
            ny = __builtin_elementwise_fma(f2s(u11.x), y,  ny);
            ny = __builtin_elementwise_fma(f2s(u11.y), ys, ny);
            A[a] = nx; A[a | MASK] = ny;
        }
    }
}

// tail perm on B's register coords (bits = d0, d9, d10, d11, d12)
__device__ __forceinline__ constexpr int permB(int ad) {
    return (ad & 1)
         | ((((ad >> 1) ^ (ad >> 2)) & 1) << 1)
         | ((((ad >> 2) ^ (ad >> 3)) & 1) << 2)
         | ((((ad >> 3) ^ (ad >> 4)) & 1) << 3)
         | ((((ad >> 4) ^  ad      ) & 1) << 4);
}

// Single transpose arr1 {0,9,10,11,12} -> arr3 {5,6,7,8,12} (T1-write + T2-read).
__device__ __forceinline__ void transpose_1to3(f2* A, f2* S, int t) {
    #pragma unroll
    for (int h = 0; h < 2; ++h) {
        __syncthreads();
        #pragma unroll
        for (int c = 0; c < 8; ++c) {
            int slot = ((t << 1) | (c << 9)) ^ (((t >> 4) & 7) << 1);
            f2 a0 = A[h*16 + 2*c], a1 = A[h*16 + 2*c + 1];
            *(float4*)&S[slot] = make_float4(a0.x, a0.y, a1.x, a1.y);
        }
        __syncthreads();
        #pragma unroll
        for (int rr = 0; rr < 16; ++rr) {
            int jj = (t & 31) | (rr << 5) | (((t >> 5) & 7) << 9);
            A[h*16 + rr] = S[jj ^ ((rr & 7) << 1)];
        }
    }
}

// Single transpose arr1 {0,9,10,11,12} -> arr2 {1,2,3,4,12} (T1-write + T1-read).
__device__ __forceinline__ void transpose_1to2(f2* A, f2* S, int t) {
    #pragma unroll
    for (int h = 0; h < 2; ++h) {
        __syncthreads();
        #pragma unroll
        for (int c = 0; c < 8; ++c) {
            int slot = ((t << 1) | (c << 9)) ^ (((t >> 4) & 7) << 1);
            f2 a0 = A[h*16 + 2*c], a1 = A[h*16 + 2*c + 1];
            *(float4*)&S[slot] = make_float4(a0.x, a0.y, a1.x, a1.y);
        }
        __syncthreads();
        #pragma unroll
        for (int rr = 0; rr < 16; ++rr) {
            int jj = (t & 1) | (rr << 1) | (((t >> 1) & 15) << 5) | (((t >> 5) & 7) << 9);
            A[h*16 + rr] = S[jj ^ (((t >> 1) & 7) << 1)];
        }
    }
}

// B gates after the arr1 phase: arr3 d5..8 -> q7,q6,q5,q4 (Ush 3..6), then store.
__device__ __forceinline__ void b_tail_gates_store(
    f2* A, f2* S, const f2 (*Ush)[4], int t, int fixb, f2* base)
{
    transpose_1to3(A, S, t);
    gate32<1>(A, Ush[3][0], Ush[3][1], Ush[3][2], Ush[3][3]);   // d5 q7
    gate32<2>(A, Ush[4][0], Ush[4][1], Ush[4][2], Ush[4][3]);   // d6 q6
    gate32<4>(A, Ush[5][0], Ush[5][1], Ush[5][2], Ush[5][3]);   // d7 q5
    gate32<8>(A, Ush[6][0], Ush[6][1], Ush[6][2], Ush[6][3]);   // d8 q4
    // direct store from arr3 (no perm)
    #pragma unroll
    for (int h = 0; h < 2; ++h) {
        #pragma unroll
        for (int rr = 0; rr < 16; ++rr) {
            int d = (t & 31) | (rr << 5) | (((t >> 5) & 7) << 9) | (h << 12);
            int m = (d & 511) | (fixb << 9) | (((d >> 9) & 1) << 12) | ((d >> 10) << 13);
            base[m] = A[h*16 + rr];
        }
    }
}

// B-sweep Ush (7): 0:q15(d10) 1:q14(d11) 2:q13(d12) 3:q7(d5) 4:q6(d6) 5:q5(d7) 6:q4(d8)
__device__ __forceinline__ int b_qb(int tt) { return (tt < 3) ? (15 - tt) : (10 - tt); }
// A-sweep Ush (9): 0:q12(j0) 1:q3(j9) 2:q2(j10) 3:q1(j11) 4:q0(j12)
//                  5:q11(j1) 6:q10(j2) 7:q9(j3) 8:q8(j4)
__device__ __forceinline__ int a_qb(int tt) { return (tt == 0) ? 12 : (tt < 5) ? (4 - tt) : (16 - tt); }

// Sweep 1: fused analytic generation + L1 x7.  No amplitude loads.
__global__ __launch_bounds__(TPB, 4) void qc_B1_gen(
    const float* __restrict__ x, const float* __restrict__ params,
    f2* __restrict__ st)
{
    __shared__ __align__(16) f2 S[4096];       // 32 KB transpose buffer
    __shared__ f2 Ush[7][4];
    __shared__ f2 V[16][2];

    const int t    = threadIdx.x;
    const int b    = blockIdx.x >> 3;
    const int fixb = blockIdx.x & 7;            // g bits 12..14
    f2* base = st + ((size_t)b << NQ);

    if (t < 16) {                               // qubit t, g bit 15-t
        f2 U[4];
        computeU(params, 0, t, U);
        float s, c;
        sincosf(0.5f * x[b*NQ + t], &s, &c);
        // w = U * (cos h, -i sin h)^T
        V[15 - t][0] = (f2){U[0].x*c + U[1].y*s, U[0].y*c - U[1].x*s};
        V[15 - t][1] = (f2){U[2].x*c + U[3].y*s, U[2].y*c - U[3].x*s};
    } else if (t < 23) {                        // layer-1 gate table (7)
        int tt = t - 16;
        computeU(params, 1, b_qb(tt), Ush[tt]);
    }
    __syncthreads();                             // V + Ush ready

    const int f0 = fixb & 1, f1 = (fixb >> 1) & 1, f2b = (fixb >> 2) & 1;
    const int t0 = t & 1,  t7 = (t >> 7) & 1;

    // pre = prod_{beta=4..13}
    f2 pre = V[4][(t ^ (t >> 1)) & 1];
    #pragma unroll
    for (int bb = 5; bb <= 10; ++bb)
        pre = cmulpk(pre, V[bb][((t >> (bb - 4)) ^ (t >> (bb - 3))) & 1]);
    pre = cmulpk(pre, V[11][t7 ^ f0]);
    pre = cmulpk(pre, V[12][f0 ^ f1]);
    pre = cmulpk(pre, V[13][f1 ^ f2b]);

    f2 P0 = cmulpk(pre, V[3][t0]);               // a0=0
    f2 P1 = cmulpk(pre, V[3][1 ^ t0]);           // a0=1
    f2 Q[4];                                     // Q[a0 + 2*e4] = P[a0]*V[2][e4]
    Q[0] = cmulpk(P0, V[2][0]); Q[1] = cmulpk(P1, V[2][0]);
    Q[2] = cmulpk(P0, V[2][1]); Q[3] = cmulpk(P1, V[2][1]);
    f2 Rr[4];                                    // Rr[e2 + 2*e3] = V[0][e2]*V[1][e3]
    Rr[0] = cmulpk(V[0][0], V[1][0]); Rr[1] = cmulpk(V[0][1], V[1][0]);
    Rr[2] = cmulpk(V[0][0], V[1][1]); Rr[3] = cmulpk(V[0][1], V[1][1]);
    f2 G0 = cmulpk(V[15][0], V[14][f2b]);        // e1=0
    f2 G1 = cmulpk(V[15][1], V[14][1 ^ f2b]);    // e1=1
    f2 TT[8];                                    // TT[e1 + 2*e2 + 4*e3]
    #pragma unroll
    for (int e = 0; e < 4; ++e) {
        TT[2*e]     = cmulpk(G0, Rr[e]);
        TT[2*e + 1] = cmulpk(G1, Rr[e]);
    }

    f2 A[32];
    #pragma unroll
    for (int a = 0; a < 32; ++a) {
        const int a0 = a & 1;
        const int e1 = ((a >> 1) ^ (a >> 2)) & 1;
        const int e2 = ((a >> 2) ^ (a >> 3)) & 1;
        const int e3 = ((a >> 3) ^ (a >> 4)) & 1;
        const int e4 = ((a >> 4) ^  a      ) & 1;
        A[a] = cmulpk(Q[a0 + 2*e4], TT[e1 + 2*e2 + 4*e3]);
    }

    // arr1 gates (layer 1): d10..12 -> q15,q14,q13
    gate32<4> (A, Ush[0][0], Ush[0][1], Ush[0][2], Ush[0][3]);
    gate32<8> (A, Ush[1][0], Ush[1][1], Ush[1][2], Ush[1][3]);
    gate32<16>(A, Ush[2][0], Ush[2][1], Ush[2][2], Ush[2][3]);

    b_tail_gates_store(A, S, Ush, t, fixb, base);
}

// Sweeps 3,5: tail(lm-1) rename + layer-lm gates on 7 B-local qubits.
__global__ __launch_bounds__(TPB, 4) void qc_B_heavy(
    const float* __restrict__ params, f2* __restrict__ st, int lm)
{
    __shared__ __align__(16) f2 S[4096];
    __shared__ f2 Ush[7][4];

    const int t    = threadIdx.x;
    const int b    = blockIdx.x >> 3;
    const int fixb = blockIdx.x & 7;            // g bits 12..14
    f2* base = st + ((size_t)b << NQ);

    if (t < 7) computeU(params, lm, b_qb(t), Ush[t]);

    // load arr1-d: reg a: bit0 = d0, bits1..4 = d9..12; thread bits = d1..8
    f2 R[32];
    #pragma unroll
    for (int k = 0; k < 16; ++k) {
        int j = 2*(t + 256*k);
        int m = (j & 511) | (fixb << 9) | (((j >> 9) & 1) << 12) | ((j >> 10) << 13);
        float4 v = *(const float4*)(base + m);
        R[2*k]   = (f2){v.x, v.y};
        R[2*k+1] = (f2){v.z, v.w};
    }
    // tail perm of layer lm-1: pure compile-time register rename
    f2 A[32];
    #pragma unroll
    for (int a = 0; a < 32; ++a) A[a] = R[permB(a)];
    __syncthreads();                             // Ush ready

    // arr1 gates (layer lm): d10..12 -> q15,q14,q13
    gate32<4> (A, Ush[0][0], Ush[0][1], Ush[0][2], Ush[0][3]);
    gate32<8> (A, Ush[1][0], Ush[1][1], Ush[1][2], Ush[1][3]);
    gate32<16>(A, Ush[2][0], Ush[2][1], Ush[2][2], Ush[2][3]);

    b_tail_gates_store(A, S, Ush, t, fixb, base);
}

// Sweeps 2,4: layer-l gates x9 (5 natural + 4 after nat->arr2 transpose)
// + main(l) perm in writeback (staged at arr2 positions).
__global__ __launch_bounds__(TPB, 4) void qc_A_lite(
    const float* __restrict__ params, f2* __restrict__ st, int layer)
{
    __shared__ __align__(16) f2 S[4096];
    __shared__ f2 Ush[9][4];
    const int t    = threadIdx.x;
    const int b    = blockIdx.x >> 3;
    const int fix3 = blockIdx.x & 7;
    f2* base = st + ((size_t)b << NQ) + (fix3 << 13);

    if (t < 9) computeU(params, layer, a_qb(t), Ush[t]);

    f2 A[32];
    const float4* src = (const float4*)base;
    #pragma unroll
    for (int k = 0; k < 16; ++k) {
        float4 v = src[t + 256*k];
        A[2*k]   = (f2){v.x, v.y};
        A[2*k+1] = (f2){v.z, v.w};
    }
    __syncthreads();                             // Ush ready

    // natural gates: j0 q12, j9 q3, j10 q2, j11 q1, j12 q0
    gate32<1> (A, Ush[0][0], Ush[0][1], Ush[0][2], Ush[0][3]);
    gate32<2> (A, Ush[1][0], Ush[1][1], Ush[1][2], Ush[1][3]);
    gate32<4> (A, Ush[2][0], Ush[2][1], Ush[2][2], Ush[2][3]);
    gate32<8> (A, Ush[3][0], Ush[3][1], Ush[3][2], Ush[3][3]);
    gate32<16>(A, Ush[4][0], Ush[4][1], Ush[4][2], Ush[4][3]);

    transpose_1to2(A, S, t);
    // arr2 gates: j1 q11, j2 q10, j3 q9, j4 q8
    gate32<1>(A, Ush[5][0], Ush[5][1], Ush[5][2], Ush[5][3]);
    gate32<2>(A, Ush[6][0], Ush[6][1], Ush[6][2], Ush[6][3]);
    gate32<4>(A, Ush[7][0], Ush[7][1], Ush[7][2], Ush[7][3]);
    gate32<8>(A, Ush[8][0], Ush[8][1], Ush[8][2], Ush[8][3]);

    // writeback: stage at arr2 positions, read with main-chain perm, store coalesced
    float4* dst = (float4*)base;
    #pragma unroll
    for (int h = 0; h < 2; ++h) {
        __syncthreads();
        #pragma unroll
        for (int rr = 0; rr < 16; ++rr) {        // arr2 positions (T2-write)
            int jj = (t & 1) | (rr << 1) | (((t >> 1) & 15) << 5) | (((t >> 5) & 7) << 9);
            S[jj ^ (((t >> 1) & 7) << 1)] = A[h*16 + rr];
        }
        __syncthreads();
        #pragma unroll
        for (int k = 0; k < 8; ++k) {            // dest d' = 2(t+256k), bit12 = h
            int d  = 2*(t + 256*k);
            int i0 = d ^ (d >> 1) ^ (h << 11);
            int i1 = (d+1) ^ ((d+1) >> 1) ^ (h << 11);
            f2 a0 = S[i0 ^ (((i0 >> 5) & 7) << 1)];
            f2 a1 = S[i1 ^ (((i1 >> 5) & 7) << 1)];
            dst[(t + 256*k) | (h << 11)] = make_float4(a0.x, a0.y, a1.x, a1.y);
        }
    }
}

// Sweep 6: L3 x9, then expZ with main3.tail3 folded as relabel.
// After nat->arr2 transpose, amp coords: u0..2 = fix3, u3 = t0, u4..7 = rr,
// u8..11 = t1..4, u12..14 = t5..7, u15 = h (reg a = rr + 16h).
// f_b = parity(u>>b) (b<=14), f15 = parity(u & 0x7FFF).
// Reg-dependent sign buckets over (rr,h):
//   B1: par(rr)^h    -> beta 0..4  (q15..q11)
//   B2: par(rr>>1)^h -> beta 5     (q10)
//   B3: par(rr>>2)^h -> beta 6     (q9)
//   B4: rr3^h        -> beta 7     (q8)
//   B5: h            -> beta 8..14 (q7..q1)
//   B6: par(rr)      -> beta 15    (q0)
__global__ __launch_bounds__(TPB, 4) void qc_A_final(
    const float* __restrict__ params, const f2* __restrict__ st,
    float* __restrict__ out)
{
    __shared__ __align__(16) f2 S[4096];         // transpose buffer, reused as F
    __shared__ f2 Ush[9][4];
    float* F = (float*)S;                         // 16*272 = 4352 floats <= 8192
    const int t    = threadIdx.x;
    const int b    = blockIdx.x >> 3;
    const int fix3 = blockIdx.x & 7;
    const f2* base = st + ((size_t)b << NQ) + (fix3 << 13);

    if (t < 9) computeU(params, 3, a_qb(t), Ush[t]);

    f2 A[32];
    const float4* src = (const float4*)base;
    #pragma unroll
    for (int k = 0; k < 16; ++k) {
        float4 v = src[t + 256*k];
        A[2*k]   = (f2){v.x, v.y};
        A[2*k+1] = (f2){v.z, v.w};
    }
    __syncthreads();

    gate32<1> (A, Ush[0][0], Ush[0][1], Ush[0][2], Ush[0][3]);  // j0  q12
    gate32<2> (A, Ush[1][0], Ush[1][1], Ush[1][2], Ush[1][3]);  // j9  q3
    gate32<4> (A, Ush[2][0], Ush[2][1], Ush[2][2], Ush[2][3]);  // j10 q2
    gate32<8> (A, Ush[3][0], Ush[3][1], Ush[3][2], Ush[3][3]);  // j11 q1
    gate32<16>(A, Ush[4][0], Ush[4][1], Ush[4][2], Ush[4][3]);  // j12 q0

    transpose_1to2(A, S, t);
    gate32<1>(A, Ush[5][0], Ush[5][1], Ush[5][2], Ush[5][3]);   // j1 q11
    gate32<2>(A, Ush[6][0], Ush[6][1], Ush[6][2], Ush[6][3]);   // j2 q10
    gate32<4>(A, Ush[7][0], Ush[7][1], Ush[7][2], Ush[7][3]);   // j3 q9
    gate32<8>(A, Ush[8][0], Ush[8][1], Ush[8][2], Ush[8][3]);   // j4 q8

    // 6 sign buckets over reg slots (rr, h)
    float B1 = 0.f, B2 = 0.f, B3 = 0.f, B4 = 0.f, B5 = 0.f, B6 = 0.f;
    #pragma unroll
    for (int h = 0; h < 2; ++h) {
        #pragma unroll
        for (int rr = 0; rr < 16; ++rr) {
            f2 v = A[h*16 + rr];
            float p = v.x*v.x + v.y*v.y;
            int pr = __popc(rr);
            B1 += ((pr ^ h) & 1)              ? -p : p;
            B2 += ((__popc(rr >> 1) ^ h) & 1) ? -p : p;
            B3 += ((__popc(rr >> 2) ^ h) & 1) ? -p : p;
            B4 += (((rr >> 3) ^ h) & 1)       ? -p : p;
            B5 += h                           ? -p : p;
            B6 += (pr & 1)                    ? -p : p;
        }
    }

    const int pt  = __popc(t) & 1;               // par(t0..7)
    const int pt1 = __popc(t >> 1) & 1;          // par(t1..7)
    const int pf  = __popc(fix3) & 1;
    float acc[NQ];
    acc[0]  = ((pf ^ pt) & 1)                  ? -B6 : B6;   // beta15
    acc[1]  = ((t >> 7) & 1)                   ? -B5 : B5;   // beta14
    acc[2]  = (__popc(t >> 6) & 1)             ? -B5 : B5;   // beta13
    acc[3]  = (__popc(t >> 5) & 1)             ? -B5 : B5;   // beta12
    acc[4]  = (__popc(t >> 4) & 1)             ? -B5 : B5;   // beta11
    acc[5]  = (__popc(t >> 3) & 1)             ? -B5 : B5;   // beta10
    acc[6]  = (__popc(t >> 2) & 1)             ? -B5 : B5;   // beta9
    acc[7]  = pt1                              ? -B5 : B5;   // beta8
    acc[8]  = pt1                              ? -B4 : B4;   // beta7
    acc[9]  = pt1                              ? -B3 : B3;   // beta6
    acc[10] = pt1                              ? -B2 : B2;   // beta5
    acc[11] = pt1                              ? -B1 : B1;   // beta4
    acc[12] = pt                               ? -B1 : B1;   // beta3
    acc[13] = ((((fix3 >> 2) & 1) ^ pt) & 1)   ? -B1 : B1;   // beta2
    acc[14] = ((__popc(fix3 >> 1) ^ pt) & 1)   ? -B1 : B1;   // beta1
    acc[15] = ((pf ^ pt) & 1)                  ? -B1 : B1;   // beta0

    __syncthreads();                             // S reads done; reuse as F
    #pragma unroll
    for (int q = 0; q < NQ; ++q) F[q*272 + t] = acc[q];
    __syncthreads();
    const int qq = t >> 4, ii = t & 15;
    float s = 0.f;
    #pragma unroll
    for (int c = 0; c < 16; ++c) s += F[qq*272 + ii + 16*c];
    s += __shfl_down(s, 8, 16);
    s += __shfl_down(s, 4, 16);
    s += __shfl_down(s, 2, 16);
    s += __shfl_down(s, 1, 16);
    if (ii == 0) atomicAdd(&out[b*NQ + qq], s);
}

extern "C" void kernel_launch(void* const* d_in, const int* in_sizes, int n_in,
                              void* d_out, int out_size, void* d_ws, size_t ws_size,
                              hipStream_t stream)
{
    (void)in_sizes; (void)n_in; (void)ws_size;
    const float* x      = (const float*)d_in[0];   // (512,16) fp32
    const float* params = (const float*)d_in[1];   // (4,16,3) fp32
    float* out = (float*)d_out;                    // (512,16) fp32
    f2* st = (f2*)d_ws;                            // 256 MiB state

    hipMemsetAsync(d_out, 0, (size_t)out_size * sizeof(float), stream);
    qc_B1_gen <<<dim3(512*8), dim3(TPB), 0, stream>>>(x, params, st);
    qc_A_lite <<<dim3(512*8), dim3(TPB), 0, stream>>>(params, st, 1);
    qc_B_heavy<<<dim3(512*8), dim3(TPB), 0, stream>>>(params, st, 2);
    qc_A_lite <<<dim3(512*8), dim3(TPB), 0, stream>>>(params, st, 2);
    qc_B_heavy<<<dim3(512*8), dim3(TPB), 0, stream>>>(params, st, 3);
    qc_A_final<<<dim3(512*8), dim3(TPB), 0, stream>>>(params, st, out);
}